// Round 13
// baseline (215.963 us; speedup 1.0000x reference)
//
#include <hip/hip_runtime.h>
#include <math.h>

#define Bn 4
#define Cn 32
#define Dn 64
#define Hn 64
#define Wn 64
#define HW (Hn * Wn)
#define DHW (Dn * Hn * Wn)      /* 262144 */
#define TOT (Bn * Cn * DHW)     /* 33554432 */
#define NCHUNK 256              /* spatial chunks per batch in reduce */

typedef float f4 __attribute__((ext_vector_type(4)));
typedef float f2 __attribute__((ext_vector_type(2)));

// ============================================================
// Kernel 1: fused reductions (atomic-free, fence-free).
// ============================================================
__global__ __launch_bounds__(256, 4) void reduce_kernel(
    const float* __restrict__ x,
    float* __restrict__ s_avg, float* __restrict__ s_max,
    float* __restrict__ part_sum, float* __restrict__ part_max) {
    const int b = blockIdx.x / NCHUNK;
    const int chunk = blockIdx.x % NCHUNK;
    const int base = chunk * 1024 + threadIdx.x * 4;
    const int lane = threadIdx.x & 63;
    const int wid = threadIdx.x >> 6;

    f4 ssum = {0.f, 0.f, 0.f, 0.f};
    f4 smax = {-INFINITY, -INFINITY, -INFINITY, -INFINITY};
    float tsum[Cn], tmax[Cn];

    const float* xp = x + (size_t)b * Cn * DHW + base;
#pragma unroll
    for (int g = 0; g < Cn / 8; ++g) {
        f4 v[8];
#pragma unroll
        for (int j = 0; j < 8; ++j)
            v[j] = *reinterpret_cast<const f4*>(xp + (size_t)(g * 8 + j) * DHW);
#pragma unroll
        for (int j = 0; j < 8; ++j) {
            const int c = g * 8 + j;
            ssum += v[j];
            smax.x = fmaxf(smax.x, v[j].x); smax.y = fmaxf(smax.y, v[j].y);
            smax.z = fmaxf(smax.z, v[j].z); smax.w = fmaxf(smax.w, v[j].w);
            tsum[c] = (v[j].x + v[j].y) + (v[j].z + v[j].w);
            tmax[c] = fmaxf(fmaxf(v[j].x, v[j].y), fmaxf(v[j].z, v[j].w));
        }
    }

    *reinterpret_cast<f4*>(s_avg + (size_t)b * DHW + base) = ssum * (1.f / Cn);
    *reinterpret_cast<f4*>(s_max + (size_t)b * DHW + base) = smax;

    __shared__ float redS[4][Cn];
    __shared__ float redM[4][Cn];
#pragma unroll
    for (int c = 0; c < Cn; ++c) {
        float ps = tsum[c], pm = tmax[c];
#pragma unroll
        for (int off = 32; off; off >>= 1) {
            ps += __shfl_xor(ps, off);
            pm = fmaxf(pm, __shfl_xor(pm, off));
        }
        if (lane == 0) { redS[wid][c] = ps; redM[wid][c] = pm; }
    }
    __syncthreads();
    if (threadIdx.x < Cn) {
        const int c = threadIdx.x;
        float s = (redS[0][c] + redS[1][c]) + (redS[2][c] + redS[3][c]);
        float m = fmaxf(fmaxf(redM[0][c], redM[1][c]),
                        fmaxf(redM[2][c], redM[3][c]));
        part_sum[(b * Cn + c) * NCHUNK + chunk] = s;
        part_max[(b * Cn + c) * NCHUNK + chunk] = m;
    }
}

// ============================================================
// Kernel 2: partial-reduce + channel-attention MLP. 1 block, 256 threads.
// ============================================================
__global__ __launch_bounds__(256) void ca_kernel(
    const float* __restrict__ part_sum, const float* __restrict__ part_max,
    const float* __restrict__ fc1_w, const float* __restrict__ fc1_b,
    const float* __restrict__ fc2_w, const float* __restrict__ fc2_b,
    float* __restrict__ ca) {
    __shared__ float inpAll[Bn][64];
    __shared__ float h[128];
    const int t = threadIdx.x;
    {
        const int which = t >> 7;        // 0: sum, 1: max
        const int b = (t >> 5) & 3;
        const int c = t & 31;
        const f4* p4 = reinterpret_cast<const f4*>(
            (which ? part_max : part_sum) + (b * Cn + c) * NCHUNK);
        if (which == 0) {
            float acc = 0.f;
#pragma unroll
            for (int i = 0; i < NCHUNK / 4; ++i) {
                f4 v = p4[i];
                acc += (v.x + v.y) + (v.z + v.w);
            }
            inpAll[b][c] = acc * (1.f / DHW);
        } else {
            float m = -INFINITY;
#pragma unroll
            for (int i = 0; i < NCHUNK / 4; ++i) {
                f4 v = p4[i];
                m = fmaxf(m, fmaxf(fmaxf(v.x, v.y), fmaxf(v.z, v.w)));
            }
            inpAll[b][Cn + c] = m;
        }
    }
    __syncthreads();
#pragma unroll 1
    for (int b = 0; b < Bn; ++b) {
        if (t < 128) {
            float acc = fc1_b[t];
#pragma unroll
            for (int k = 0; k < 64; ++k) acc += fc1_w[t * 64 + k] * inpAll[b][k];
            h[t] = fmaxf(acc, 0.f);
        }
        __syncthreads();
        if (t < Cn) {
            float a2 = fc2_b[t];
#pragma unroll
            for (int k = 0; k < 128; ++k) a2 += fc2_w[t * 128 + k] * h[k];
            ca[b * Cn + t] = 1.f / (1.f + expf(-a2));
        }
        __syncthreads();
    }
}

// ============================================================
// Kernel 3: conv + epilogue, x-in-registers + packed-f32 FMA.
//  Tile 32x * 4y * 8z, 128 threads, SEQUENTIAL-ic through one 22.4 KB
//  halo buffer -> 1024 blocks, 4 resident/CU (desynced blocks overlap
//  one block's store burst with others' FMA — R9/R10 lesson).
//  Thread = (xq, ly, zh): 4-aligned-x quad x 2 z, 4 oc.
//  Inner: 3 ds_read_b128 per z-row (sliding window); weights via
//  wave-uniform s_load pairs; acc packed f2 over oc-pairs so the FMA
//  lowers to v_pk_fma_f32 (2x f32 rate — the 157TF path).
// ============================================================
#define TXc 32
#define TYc 4
#define TZc 8
#define LXc 40          /* 38 used, padded for 16B alignment */
#define LYc (TYc + 6)   /* 10 */
#define LZc (TZc + 6)   /* 14 */
#define HALO1 (LZc * LYc * LXc)  /* 5600 floats = 22.4 KB */

__global__ __launch_bounds__(128) void conv_kernel(
    const float* __restrict__ ca_g,
    const float* __restrict__ s_avg, const float* __restrict__ s_max,
    const float* __restrict__ w1, const float* __restrict__ w2,
    float* __restrict__ out) {
    __shared__ __align__(16) float sIn[HALO1];   // 22.4 KB
    __shared__ float ca_s[Cn];

    const int t = threadIdx.x;
    const int bid = blockIdx.x;
    const int b = bid >> 8;            // 256 tiles per batch
    const int tile = bid & 255;
    const int txi = tile & 1, tyi = (tile >> 1) & 15, tzi = tile >> 5;
    const int x0 = txi * TXc, y0 = tyi * TYc, z0 = tzi * TZc;

    if (t < Cn) ca_s[t] = ca_g[b * Cn + t];

    const float* srcA = s_avg + (size_t)b * DHW;
    const float* srcM = s_max + (size_t)b * DHW;

    const int xq = t & 7, ly = (t >> 3) & 3, zh = t >> 5;  // zh in [0,4)
    const int xb = xq * 4;

    f2 acc01[2][4], acc23[2][4];  // [z2][j], lanes = (oc0,oc1)/(oc2,oc3)
#pragma unroll
    for (int z2 = 0; z2 < 2; ++z2)
#pragma unroll
        for (int j = 0; j < 4; ++j) {
            acc01[z2][j] = (f2){0.f, 0.f};
            acc23[z2][j] = (f2){0.f, 0.f};
        }

#pragma unroll 1
    for (int ic = 0; ic < 2; ++ic) {
        __syncthreads();  // protect sIn reuse
        const float* src = ic ? srcM : srcA;
        for (int i = t; i < HALO1; i += 128) {
            const int zz = i / (LYc * LXc);
            const int r2 = i - zz * (LYc * LXc);
            const int yy = r2 / LXc;
            const int xx = r2 - yy * LXc;
            const int gz = z0 + zz - 3, gy = y0 + yy - 3, gx = x0 + xx - 3;
            float v = 0.f;
            if ((unsigned)gz < (unsigned)Dn && (unsigned)gy < (unsigned)Hn &&
                (unsigned)gx < (unsigned)Wn)
                v = src[(gz * Hn + gy) * Wn + gx];
            sIn[i] = v;
        }
        __syncthreads();

#pragma unroll 1
        for (int kh = 0; kh < 7; ++kh) {
            const int rowbase = (ly + kh) * LXc + xb;
            float wa[12], wb[12];
            {
                const f4* rp = reinterpret_cast<const f4*>(
                    sIn + rowbase + (2 * zh) * (LYc * LXc));
                const f4 r0 = rp[0], r1 = rp[1], r2 = rp[2];
                wa[0] = r0.x; wa[1] = r0.y; wa[2] = r0.z; wa[3] = r0.w;
                wa[4] = r1.x; wa[5] = r1.y; wa[6] = r1.z; wa[7] = r1.w;
                wa[8] = r2.x; wa[9] = r2.y; wa[10] = r2.z; wa[11] = r2.w;
            }
#pragma unroll
            for (int kd = 0; kd < 7; ++kd) {
                float* cur = (kd & 1) ? wb : wa;   // row 2zh+kd
                float* nxt = (kd & 1) ? wa : wb;   // row 2zh+kd+1
                {
                    const f4* rp = reinterpret_cast<const f4*>(
                        sIn + rowbase + (2 * zh + kd + 1) * (LYc * LXc));
                    const f4 r0 = rp[0], r1 = rp[1], r2 = rp[2];
                    nxt[0] = r0.x; nxt[1] = r0.y; nxt[2] = r0.z; nxt[3] = r0.w;
                    nxt[4] = r1.x; nxt[5] = r1.y; nxt[6] = r1.z; nxt[7] = r1.w;
                    nxt[8] = r2.x; nxt[9] = r2.y; nxt[10] = r2.z; nxt[11] = r2.w;
                }
                const float* wp = w1 + ic * 343 + kd * 49 + kh * 7;
#pragma unroll
                for (int kw = 0; kw < 7; ++kw) {
                    // wave-uniform -> s_load pairs; VOP3P scalar operand
                    const f2 w01 = {wp[kw], wp[686 + kw]};
                    const f2 w23 = {wp[1372 + kw], wp[2058 + kw]};
#pragma unroll
                    for (int j = 0; j < 4; ++j) {
                        const float iv0 = cur[j + kw];
                        const float iv1 = nxt[j + kw];
                        acc01[0][j] += w01 * iv0;   // v_pk_fma_f32
                        acc23[0][j] += w23 * iv0;
                        acc01[1][j] += w01 * iv1;
                        acc23[1][j] += w23 * iv1;
                    }
                }
            }
        }
    }

    // ---- 1x1 conv + sigmoid ----
    const float c20 = w2[0], c21 = w2[1], c22 = w2[2], c23 = w2[3];
    f4 sv[2];
#pragma unroll
    for (int z2 = 0; z2 < 2; ++z2)
#pragma unroll
        for (int j = 0; j < 4; ++j) {
            float s = fmaxf(acc01[z2][j].x, 0.f) * c20 +
                      fmaxf(acc01[z2][j].y, 0.f) * c21 +
                      fmaxf(acc23[z2][j].x, 0.f) * c22 +
                      fmaxf(acc23[z2][j].y, 0.f) * c23;
            sv[z2][j] = 1.f / (1.f + expf(-s));
        }

    // ---- NT f4 stores from registers ----
    const size_t base0 = (size_t)b * Cn * DHW + (size_t)(z0 + 2 * zh) * HW +
                         (size_t)(y0 + ly) * Wn + (x0 + xb);
    f4* outp = reinterpret_cast<f4*>(out);
#pragma unroll 1
    for (int c = 0; c < Cn; ++c) {
        const float cav = ca_s[c];
        const size_t cb4 = (base0 + (size_t)c * DHW) >> 2;
#pragma unroll
        for (int z2 = 0; z2 < 2; ++z2) {
            const f4 a = sv[z2] * cav;
            const f4 an = 1.f - a;
            __builtin_nontemporal_store(a, outp + cb4 + z2 * (HW / 4));
            __builtin_nontemporal_store(an, outp + (TOT / 4) + cb4 + z2 * (HW / 4));
        }
    }
}

extern "C" void kernel_launch(void* const* d_in, const int* in_sizes, int n_in,
                              void* d_out, int out_size, void* d_ws,
                              size_t ws_size, hipStream_t stream) {
    const float* x = (const float*)d_in[0];
    const float* fc1_w = (const float*)d_in[1];
    const float* fc1_b = (const float*)d_in[2];
    const float* fc2_w = (const float*)d_in[3];
    const float* fc2_b = (const float*)d_in[4];
    const float* conv1_w = (const float*)d_in[5];
    const float* conv2_w = (const float*)d_in[6];

    float* ws = (float*)d_ws;
    float* s_avg = ws;                               // B*DHW
    float* s_max = s_avg + (size_t)Bn * DHW;         // B*DHW
    float* part_sum = s_max + (size_t)Bn * DHW;      // B*C*NCHUNK
    float* part_max = part_sum + Bn * Cn * NCHUNK;   // B*C*NCHUNK
    float* ca = part_max + Bn * Cn * NCHUNK;         // B*C

    reduce_kernel<<<Bn * NCHUNK, 256, 0, stream>>>(x, s_avg, s_max, part_sum,
                                                   part_max);
    ca_kernel<<<1, 256, 0, stream>>>(part_sum, part_max, fc1_w, fc1_b, fc2_w,
                                     fc2_b, ca);
    conv_kernel<<<Bn * 256, 128, 0, stream>>>(ca, s_avg, s_max, conv1_w,
                                              conv2_w, (float*)d_out);
}

// Round 14
// 205.325 us; speedup vs baseline: 1.0518x; 1.0518x over previous
//
#include <hip/hip_runtime.h>
#include <math.h>

#define Bn 4
#define Cn 32
#define Dn 64
#define Hn 64
#define Wn 64
#define HW (Hn * Wn)
#define DHW (Dn * Hn * Wn)      /* 262144 */
#define TOT (Bn * Cn * DHW)     /* 33554432 */
#define NCHUNK 256              /* spatial chunks per batch in reduce */

typedef float f4 __attribute__((ext_vector_type(4)));

// ============================================================
// Kernel 1: fused reductions (R8 version — measured-good; VGPR ~84,
// no launch_bounds min-wave cap: R10-13's 8-wide batch + cap spilled).
// ============================================================
__global__ __launch_bounds__(256) void reduce_kernel(
    const float* __restrict__ x,
    float* __restrict__ s_avg, float* __restrict__ s_max,
    float* __restrict__ part_sum, float* __restrict__ part_max) {
    const int b = blockIdx.x / NCHUNK;
    const int chunk = blockIdx.x % NCHUNK;
    const int base = chunk * 1024 + threadIdx.x * 4;
    const int lane = threadIdx.x & 63;
    const int wid = threadIdx.x >> 6;

    f4 ssum = {0.f, 0.f, 0.f, 0.f};
    f4 smax = {-INFINITY, -INFINITY, -INFINITY, -INFINITY};
    float tsum[Cn], tmax[Cn];

    const float* xp = x + (size_t)b * Cn * DHW + base;
#pragma unroll
    for (int c = 0; c < Cn; ++c) {
        const f4 v = *reinterpret_cast<const f4*>(xp + (size_t)c * DHW);
        ssum += v;
        smax.x = fmaxf(smax.x, v.x); smax.y = fmaxf(smax.y, v.y);
        smax.z = fmaxf(smax.z, v.z); smax.w = fmaxf(smax.w, v.w);
        tsum[c] = (v.x + v.y) + (v.z + v.w);
        tmax[c] = fmaxf(fmaxf(v.x, v.y), fmaxf(v.z, v.w));
    }

    *reinterpret_cast<f4*>(s_avg + (size_t)b * DHW + base) = ssum * (1.f / Cn);
    *reinterpret_cast<f4*>(s_max + (size_t)b * DHW + base) = smax;

    __shared__ float redS[4][Cn];
    __shared__ float redM[4][Cn];
#pragma unroll
    for (int c = 0; c < Cn; ++c) {
        float ps = tsum[c], pm = tmax[c];
#pragma unroll
        for (int off = 32; off; off >>= 1) {
            ps += __shfl_xor(ps, off);
            pm = fmaxf(pm, __shfl_xor(pm, off));
        }
        if (lane == 0) { redS[wid][c] = ps; redM[wid][c] = pm; }
    }
    __syncthreads();
    if (threadIdx.x < Cn) {
        const int c = threadIdx.x;
        float s = (redS[0][c] + redS[1][c]) + (redS[2][c] + redS[3][c]);
        float m = fmaxf(fmaxf(redM[0][c], redM[1][c]),
                        fmaxf(redM[2][c], redM[3][c]));
        part_sum[(b * Cn + c) * NCHUNK + chunk] = s;
        part_max[(b * Cn + c) * NCHUNK + chunk] = m;
    }
}

// ============================================================
// Kernel 2: partial-reduce + channel-attention MLP. 1 block, 256 threads.
// ============================================================
__global__ __launch_bounds__(256) void ca_kernel(
    const float* __restrict__ part_sum, const float* __restrict__ part_max,
    const float* __restrict__ fc1_w, const float* __restrict__ fc1_b,
    const float* __restrict__ fc2_w, const float* __restrict__ fc2_b,
    float* __restrict__ ca) {
    __shared__ float inpAll[Bn][64];
    __shared__ float h[128];
    const int t = threadIdx.x;
    {
        const int which = t >> 7;        // 0: sum, 1: max
        const int b = (t >> 5) & 3;
        const int c = t & 31;
        const f4* p4 = reinterpret_cast<const f4*>(
            (which ? part_max : part_sum) + (b * Cn + c) * NCHUNK);
        if (which == 0) {
            float acc = 0.f;
#pragma unroll
            for (int i = 0; i < NCHUNK / 4; ++i) {
                f4 v = p4[i];
                acc += (v.x + v.y) + (v.z + v.w);
            }
            inpAll[b][c] = acc * (1.f / DHW);
        } else {
            float m = -INFINITY;
#pragma unroll
            for (int i = 0; i < NCHUNK / 4; ++i) {
                f4 v = p4[i];
                m = fmaxf(m, fmaxf(fmaxf(v.x, v.y), fmaxf(v.z, v.w)));
            }
            inpAll[b][Cn + c] = m;
        }
    }
    __syncthreads();
#pragma unroll 1
    for (int b = 0; b < Bn; ++b) {
        if (t < 128) {
            float acc = fc1_b[t];
#pragma unroll
            for (int k = 0; k < 64; ++k) acc += fc1_w[t * 64 + k] * inpAll[b][k];
            h[t] = fmaxf(acc, 0.f);
        }
        __syncthreads();
        if (t < Cn) {
            float a2 = fc2_b[t];
#pragma unroll
            for (int k = 0; k < 128; ++k) a2 += fc2_w[t * 128 + k] * h[k];
            ca[b * Cn + t] = 1.f / (1.f + expf(-a2));
        }
        __syncthreads();
    }
}

// ============================================================
// Kernel 3: conv ONLY -> sa[B,DHW] (4 MB).  R6/R8 structure (measured-
// good): tile 64x*4y*4z, both-ic halo 56 KB, wave-uniform s_load weights.
// De-fused: 97% of the stores left this kernel -> no store-drain stall.
// ============================================================
#define TZc 4
#define TYc 4
#define LXc (Wn + 6)   /* 70 */
#define LYc (TYc + 6)  /* 10 */
#define LZc (TZc + 6)  /* 10 */
#define HALO1 (LZc * LYc * LXc)  /* 7000 */

__global__ __launch_bounds__(256) void conv_kernel(
    const float* __restrict__ s_avg, const float* __restrict__ s_max,
    const float* __restrict__ w1, const float* __restrict__ w2,
    float* __restrict__ sa) {
    __shared__ float sIn[2 * HALO1];          // 56 KB

    const int t = threadIdx.x;
    const int bid = blockIdx.x;
    const int b = bid >> 8;            // 256 tiles per batch
    const int tile = bid & 255;
    const int tz = tile >> 4, ty = tile & 15;
    const int z0 = tz * TZc, y0 = ty * TYc;

    // ---- load both halo buffers ----
    const float* srcA = s_avg + (size_t)b * DHW;
    const float* srcM = s_max + (size_t)b * DHW;
    for (int i = t; i < 2 * HALO1; i += 256) {
        const int ic = i / HALO1;
        const int r0 = i - ic * HALO1;
        const int xx = r0 % LXc;
        const int rem = r0 / LXc;
        const int yy = rem % LYc;
        const int zz = rem / LYc;
        const int gz = z0 + zz - 3, gy = y0 + yy - 3, gx = xx - 3;
        float v = 0.f;
        if ((unsigned)gz < (unsigned)Dn && (unsigned)gy < (unsigned)Hn &&
            (unsigned)gx < (unsigned)Wn)
            v = (ic ? srcM : srcA)[(gz * Hn + gy) * Wn + gx];
        sIn[i] = v;
    }
    __syncthreads();

    // ---- compute: thread (lx, ly) owns full z-column of 4 outputs ----
    const int lx = t & 63, ly = t >> 6;

    float acc[4][TZc];  // [oc][oz]
#pragma unroll
    for (int oc = 0; oc < 4; ++oc)
#pragma unroll
        for (int o = 0; o < TZc; ++o) acc[oc][o] = 0.f;

#pragma unroll 1
    for (int ic = 0; ic < 2; ++ic)
#pragma unroll 1
        for (int kh = 0; kh < 7; ++kh)
#pragma unroll 1
            for (int kw = 0; kw < 7; ++kw) {
                float incol[LZc];
#pragma unroll
                for (int s = 0; s < LZc; ++s)
                    incol[s] = sIn[ic * HALO1 +
                                   (s * LYc + (ly + kh)) * LXc + (lx + kw)];
#pragma unroll
                for (int kd = 0; kd < 7; ++kd)
#pragma unroll
                    for (int oc = 0; oc < 4; ++oc) {
                        // wave-uniform address -> scalar load
                        float w = w1[(((oc * 2 + ic) * 7 + kd) * 7 + kh) * 7 + kw];
#pragma unroll
                        for (int o = 0; o < TZc; ++o)
                            acc[oc][o] += incol[o + kd] * w;
                    }
            }

    const float c20 = w2[0], c21 = w2[1], c22 = w2[2], c23 = w2[3];
#pragma unroll
    for (int o = 0; o < TZc; ++o) {
        float s = fmaxf(acc[0][o], 0.f) * c20 + fmaxf(acc[1][o], 0.f) * c21 +
                  fmaxf(acc[2][o], 0.f) * c22 + fmaxf(acc[3][o], 0.f) * c23;
        sa[(size_t)b * DHW + (size_t)(z0 + o) * HW + (size_t)(y0 + ly) * Wn +
           lx] = 1.f / (1.f + expf(-s));
    }
}

// ============================================================
// Kernel 4: broadcast epilogue — the ONLY big-store kernel.
//  2048 blocks grid-stride; f4 NT stores (fills prove 7 TB/s is real);
//  sa (4 MB) re-read from L2; ca wave-uniform -> s_load.
// ============================================================
__global__ __launch_bounds__(256) void final_kernel(
    const float* __restrict__ sa, const float* __restrict__ ca,
    f4* __restrict__ out) {
    const int n4 = TOT / 4;  // 8388608
    const int stride = gridDim.x * blockDim.x;
    for (int i = blockIdx.x * blockDim.x + threadIdx.x; i < n4; i += stride) {
        const int bc = i >> 16;        // wave-uniform
        const int sp4 = i & 65535;
        const int b = bc >> 5;
        const float cav = ca[bc];
        const f4 s4 = reinterpret_cast<const f4*>(sa)[(b << 16) + sp4];
        const f4 att = s4 * cav;
        const f4 anti = 1.f - att;
        __builtin_nontemporal_store(att, &out[i]);
        __builtin_nontemporal_store(anti, &out[n4 + i]);
    }
}

extern "C" void kernel_launch(void* const* d_in, const int* in_sizes, int n_in,
                              void* d_out, int out_size, void* d_ws,
                              size_t ws_size, hipStream_t stream) {
    const float* x = (const float*)d_in[0];
    const float* fc1_w = (const float*)d_in[1];
    const float* fc1_b = (const float*)d_in[2];
    const float* fc2_w = (const float*)d_in[3];
    const float* fc2_b = (const float*)d_in[4];
    const float* conv1_w = (const float*)d_in[5];
    const float* conv2_w = (const float*)d_in[6];

    float* ws = (float*)d_ws;
    float* s_avg = ws;                               // B*DHW
    float* s_max = s_avg + (size_t)Bn * DHW;         // B*DHW
    float* sa = s_max + (size_t)Bn * DHW;            // B*DHW
    float* part_sum = sa + (size_t)Bn * DHW;         // B*C*NCHUNK
    float* part_max = part_sum + Bn * Cn * NCHUNK;   // B*C*NCHUNK
    float* ca = part_max + Bn * Cn * NCHUNK;         // B*C

    reduce_kernel<<<Bn * NCHUNK, 256, 0, stream>>>(x, s_avg, s_max, part_sum,
                                                   part_max);
    ca_kernel<<<1, 256, 0, stream>>>(part_sum, part_max, fc1_w, fc1_b, fc2_w,
                                     fc2_b, ca);
    conv_kernel<<<Bn * 256, 256, 0, stream>>>(s_avg, s_max, conv1_w, conv2_w,
                                              sa);
    final_kernel<<<2048, 256, 0, stream>>>(sa, ca, (f4*)d_out);
}

// Round 15
// 159.303 us; speedup vs baseline: 1.3557x; 1.2889x over previous
//
#include <hip/hip_runtime.h>
#include <math.h>

#define Bn 4
#define Cn 32
#define Dn 64
#define Hn 64
#define Wn 64
#define HW (Hn * Wn)
#define DHW (Dn * Hn * Wn)      /* 262144 */
#define TOT (Bn * Cn * DHW)     /* 33554432 */
#define NCHUNK 128              /* spatial chunks per batch in reduce */

typedef float f4 __attribute__((ext_vector_type(4)));

// ============================================================
// Kernel 1: fused reductions — R9-measured variant (~30 us).
// 512 blocks; each covers 2048 consecutive spatial x 32 channels,
// two f4 loads per channel for ILP. No atomics, no fences.
// ============================================================
__global__ __launch_bounds__(256) void reduce_kernel(
    const float* __restrict__ x,
    float* __restrict__ s_avg, float* __restrict__ s_max,
    float* __restrict__ part_sum, float* __restrict__ part_max) {
    const int b = blockIdx.x / NCHUNK;
    const int chunk = blockIdx.x % NCHUNK;
    const int base = chunk * 2048 + threadIdx.x * 4;
    const int lane = threadIdx.x & 63;
    const int wid = threadIdx.x >> 6;

    f4 ssum0 = {0.f, 0.f, 0.f, 0.f}, ssum1 = {0.f, 0.f, 0.f, 0.f};
    f4 smax0 = {-INFINITY, -INFINITY, -INFINITY, -INFINITY};
    f4 smax1 = smax0;
    float tsum[Cn], tmax[Cn];

    const float* xp = x + (size_t)b * Cn * DHW + base;
#pragma unroll
    for (int c = 0; c < Cn; ++c) {
        const f4 v0 = *reinterpret_cast<const f4*>(xp + (size_t)c * DHW);
        const f4 v1 = *reinterpret_cast<const f4*>(xp + (size_t)c * DHW + 1024);
        ssum0 += v0; ssum1 += v1;
        smax0.x = fmaxf(smax0.x, v0.x); smax0.y = fmaxf(smax0.y, v0.y);
        smax0.z = fmaxf(smax0.z, v0.z); smax0.w = fmaxf(smax0.w, v0.w);
        smax1.x = fmaxf(smax1.x, v1.x); smax1.y = fmaxf(smax1.y, v1.y);
        smax1.z = fmaxf(smax1.z, v1.z); smax1.w = fmaxf(smax1.w, v1.w);
        const float s0 = (v0.x + v0.y) + (v0.z + v0.w);
        const float s1 = (v1.x + v1.y) + (v1.z + v1.w);
        tsum[c] = s0 + s1;
        const float m0 = fmaxf(fmaxf(v0.x, v0.y), fmaxf(v0.z, v0.w));
        const float m1 = fmaxf(fmaxf(v1.x, v1.y), fmaxf(v1.z, v1.w));
        tmax[c] = fmaxf(m0, m1);
    }

    float* avp = s_avg + (size_t)b * DHW + base;
    float* mxp = s_max + (size_t)b * DHW + base;
    *reinterpret_cast<f4*>(avp) = ssum0 * (1.f / Cn);
    *reinterpret_cast<f4*>(avp + 1024) = ssum1 * (1.f / Cn);
    *reinterpret_cast<f4*>(mxp) = smax0;
    *reinterpret_cast<f4*>(mxp + 1024) = smax1;

    __shared__ float redS[4][Cn];
    __shared__ float redM[4][Cn];
#pragma unroll
    for (int c = 0; c < Cn; ++c) {
        float ps = tsum[c], pm = tmax[c];
#pragma unroll
        for (int off = 32; off; off >>= 1) {
            ps += __shfl_xor(ps, off);
            pm = fmaxf(pm, __shfl_xor(pm, off));
        }
        if (lane == 0) { redS[wid][c] = ps; redM[wid][c] = pm; }
    }
    __syncthreads();
    if (threadIdx.x < Cn) {
        const int c = threadIdx.x;
        float s = (redS[0][c] + redS[1][c]) + (redS[2][c] + redS[3][c]);
        float m = fmaxf(fmaxf(redM[0][c], redM[1][c]),
                        fmaxf(redM[2][c], redM[3][c]));
        part_sum[(b * Cn + c) * NCHUNK + chunk] = s;
        part_max[(b * Cn + c) * NCHUNK + chunk] = m;
    }
}

// ============================================================
// Kernel 2: partial-reduce + channel-attention MLP. 1 block, 256 threads.
// ============================================================
__global__ __launch_bounds__(256) void ca_kernel(
    const float* __restrict__ part_sum, const float* __restrict__ part_max,
    const float* __restrict__ fc1_w, const float* __restrict__ fc1_b,
    const float* __restrict__ fc2_w, const float* __restrict__ fc2_b,
    float* __restrict__ ca) {
    __shared__ float inpAll[Bn][64];
    __shared__ float h[128];
    const int t = threadIdx.x;
    {
        const int which = t >> 7;        // 0: sum, 1: max
        const int b = (t >> 5) & 3;
        const int c = t & 31;
        const f4* p4 = reinterpret_cast<const f4*>(
            (which ? part_max : part_sum) + (b * Cn + c) * NCHUNK);
        if (which == 0) {
            float acc = 0.f;
#pragma unroll
            for (int i = 0; i < NCHUNK / 4; ++i) {
                f4 v = p4[i];
                acc += (v.x + v.y) + (v.z + v.w);
            }
            inpAll[b][c] = acc * (1.f / DHW);
        } else {
            float m = -INFINITY;
#pragma unroll
            for (int i = 0; i < NCHUNK / 4; ++i) {
                f4 v = p4[i];
                m = fmaxf(m, fmaxf(fmaxf(v.x, v.y), fmaxf(v.z, v.w)));
            }
            inpAll[b][Cn + c] = m;
        }
    }
    __syncthreads();
#pragma unroll 1
    for (int b = 0; b < Bn; ++b) {
        if (t < 128) {
            float acc = fc1_b[t];
#pragma unroll
            for (int k = 0; k < 64; ++k) acc += fc1_w[t * 64 + k] * inpAll[b][k];
            h[t] = fmaxf(acc, 0.f);
        }
        __syncthreads();
        if (t < Cn) {
            float a2 = fc2_b[t];
#pragma unroll
            for (int k = 0; k < 128; ++k) a2 += fc2_w[t * 128 + k] * h[k];
            ca[b * Cn + t] = 1.f / (1.f + expf(-a2));
        }
        __syncthreads();
    }
}

// ============================================================
// Kernel 3: conv + epilogue, fused (R8 structure) with SEQUENTIAL-ic
// halo staging: one 28 KB buffer reused for ic=0,1.
//  LDS 56 -> 32.2 KB  =>  4 blocks/CU = 4 waves/SIMD (was 2).
//  Mechanism: inner loop's ds_read->FMA dependency stalls ~120cyc per
//  group; 4 waves/SIMD hides it (R14 diagnosis: VALUBusy 47%, DS-latency
//  bound). Per-thread work & arithmetic order IDENTICAL to R8.
// ============================================================
#define TZc 4
#define TYc 4
#define LXc (Wn + 6)   /* 70 */
#define LYc (TYc + 6)  /* 10 */
#define LZc (TZc + 6)  /* 10 */
#define HALO1 (LZc * LYc * LXc)  /* 7000 floats = 28 KB */

__global__ __launch_bounds__(256) void conv_kernel(
    const float* __restrict__ ca_g,
    const float* __restrict__ s_avg, const float* __restrict__ s_max,
    const float* __restrict__ w1, const float* __restrict__ w2,
    float* __restrict__ out) {
    __shared__ float sIn[HALO1];              // 28 KB (reused per ic)
    __shared__ float sv_s[TZc * TYc * Wn];    // 1024 floats, 4 KB
    __shared__ float ca_s[Cn];

    const int t = threadIdx.x;
    const int bid = blockIdx.x;
    const int b = bid >> 8;            // 256 tiles per batch
    const int tile = bid & 255;
    const int tz = tile >> 4, ty = tile & 15;
    const int z0 = tz * TZc, y0 = ty * TYc;

    if (t < Cn) ca_s[t] = ca_g[b * Cn + t];

    const float* srcA = s_avg + (size_t)b * DHW;
    const float* srcM = s_max + (size_t)b * DHW;

    const int lx = t & 63, ly = t >> 6;

    float acc[4][TZc];  // [oc][oz]
#pragma unroll
    for (int oc = 0; oc < 4; ++oc)
#pragma unroll
        for (int o = 0; o < TZc; ++o) acc[oc][o] = 0.f;

#pragma unroll 1
    for (int ic = 0; ic < 2; ++ic) {
        __syncthreads();  // protect sIn reuse (iter 0: orders ca_s too)
        const float* src = ic ? srcM : srcA;
        for (int i = t; i < HALO1; i += 256) {
            const int xx = i % LXc;
            const int rem = i / LXc;
            const int yy = rem % LYc;
            const int zz = rem / LYc;
            const int gz = z0 + zz - 3, gy = y0 + yy - 3, gx = xx - 3;
            float v = 0.f;
            if ((unsigned)gz < (unsigned)Dn && (unsigned)gy < (unsigned)Hn &&
                (unsigned)gx < (unsigned)Wn)
                v = src[(gz * Hn + gy) * Wn + gx];
            sIn[i] = v;
        }
        __syncthreads();

#pragma unroll 1
        for (int kh = 0; kh < 7; ++kh)
#pragma unroll 1
            for (int kw = 0; kw < 7; ++kw) {
                float incol[LZc];
#pragma unroll
                for (int s = 0; s < LZc; ++s)
                    incol[s] = sIn[(s * LYc + (ly + kh)) * LXc + (lx + kw)];
#pragma unroll
                for (int kd = 0; kd < 7; ++kd)
#pragma unroll
                    for (int oc = 0; oc < 4; ++oc) {
                        // wave-uniform address -> scalar load
                        float w = w1[(((oc * 2 + ic) * 7 + kd) * 7 + kh) * 7 + kw];
#pragma unroll
                        for (int o = 0; o < TZc; ++o)
                            acc[oc][o] += incol[o + kd] * w;
                    }
            }
    }

    const float c20 = w2[0], c21 = w2[1], c22 = w2[2], c23 = w2[3];
#pragma unroll
    for (int o = 0; o < TZc; ++o) {
        float s = fmaxf(acc[0][o], 0.f) * c20 + fmaxf(acc[1][o], 0.f) * c21 +
                  fmaxf(acc[2][o], 0.f) * c22 + fmaxf(acc[3][o], 0.f) * c23;
        sv_s[(o * TYc + ly) * Wn + lx] = 1.f / (1.f + expf(-s));
    }
    __syncthreads();

    // ---- epilogue: per combo a wave writes 1KB contiguous per stream ----
    const int wv = t >> 6, ln = t & 63;
    const f4* sv4 = reinterpret_cast<const f4*>(sv_s);
    f4* out4 = reinterpret_cast<f4*>(out);
    const size_t totq4 = TOT / 4;
#pragma unroll 1
    for (int combo = wv; combo < Cn * TZc; combo += 4) {
        const int c = combo >> 2, oz = combo & 3;
        const float cav = ca_s[c];
        const f4 v = sv4[oz * 64 + ln];
        const f4 att = v * cav;
        const f4 anti = 1.f - att;
        const size_t off = (((size_t)(b * Cn + c) * DHW) >> 2) +
                           (size_t)(z0 + oz) * (HW / 4) +
                           (size_t)y0 * (Wn / 4) + ln;
        __builtin_nontemporal_store(att, &out4[off]);
        __builtin_nontemporal_store(anti, &out4[totq4 + off]);
    }
}

extern "C" void kernel_launch(void* const* d_in, const int* in_sizes, int n_in,
                              void* d_out, int out_size, void* d_ws,
                              size_t ws_size, hipStream_t stream) {
    const float* x = (const float*)d_in[0];
    const float* fc1_w = (const float*)d_in[1];
    const float* fc1_b = (const float*)d_in[2];
    const float* fc2_w = (const float*)d_in[3];
    const float* fc2_b = (const float*)d_in[4];
    const float* conv1_w = (const float*)d_in[5];
    const float* conv2_w = (const float*)d_in[6];

    float* ws = (float*)d_ws;
    float* s_avg = ws;                               // B*DHW
    float* s_max = s_avg + (size_t)Bn * DHW;         // B*DHW
    float* part_sum = s_max + (size_t)Bn * DHW;      // B*C*NCHUNK
    float* part_max = part_sum + Bn * Cn * NCHUNK;   // B*C*NCHUNK
    float* ca = part_max + Bn * Cn * NCHUNK;         // B*C

    reduce_kernel<<<Bn * NCHUNK, 256, 0, stream>>>(x, s_avg, s_max, part_sum,
                                                   part_max);
    ca_kernel<<<1, 256, 0, stream>>>(part_sum, part_max, fc1_w, fc1_b, fc2_w,
                                     fc2_b, ca);
    conv_kernel<<<Bn * 256, 256, 0, stream>>>(ca, s_avg, s_max, conv1_w,
                                              conv2_w, (float*)d_out);
}